// Round 11
// baseline (4271.238 us; speedup 1.0000x reference)
//
#include <hip/hip_runtime.h>

typedef unsigned short u16;
typedef float f32x4 __attribute__((ext_vector_type(4)));
typedef short s16x8 __attribute__((ext_vector_type(8)));

#define T_TOK   16448L   // 257*64
#define D_DIM   768L
#define H_DIM   3072L
#define E_NUM   8L
#define M_PAD   16512L   // halves: A=8192 rows (64 tiles), B=8320 rows (65 tiles)

// per-expert block layout in the mega dispatch
#define G1A 1536   // 64*24
#define G2A 384    // 64*6
#define G1B 1560   // 65*24
#define G2B 390    // 65*6
#define PE  3872   // 3870 padded to mult of 8

// ---------- helpers ----------
__device__ __forceinline__ u16 f2bf(float f){
  unsigned u = __float_as_uint(f);
  u = u + 0x7FFFu + ((u >> 16) & 1u);          // RNE
  return (u16)(u >> 16);
}
__device__ __forceinline__ unsigned f2bf2(float a, float b){
  return (unsigned)f2bf(a) | ((unsigned)f2bf(b) << 16);
}

__device__ __forceinline__ void gload_lds16(const u16* g, u16* s){
  __builtin_amdgcn_global_load_lds((const __attribute__((address_space(1))) void*)g,
                                   (__attribute__((address_space(3))) void*)s,
                                   16, 0, 0);
}

// bijective XCD chunking (m204)
__device__ __forceinline__ int xcd_chunk(int idx, int n){
  const int q = n >> 3, r = n & 7, x = idx & 7;
  return (x < r ? x*(q+1) : r*(q+1) + (x-r)*q) + (idx >> 3);
}

// ---------- cross-XCD sync primitives (agent scope; LLC-side polls) ----------
__device__ __forceinline__ void spin_ge(const int* p, int need){
  if (threadIdx.x == 0){
    while (__hip_atomic_load(p, __ATOMIC_RELAXED, __HIP_MEMORY_SCOPE_AGENT) < need)
      __builtin_amdgcn_s_sleep(16);
  }
  __syncthreads();
  __builtin_amdgcn_fence(__ATOMIC_ACQUIRE, "agent");   // invalidate stale L1/L2
}
__device__ __forceinline__ void spin_eq(const int* p, int want){
  if (threadIdx.x == 0){
    while (__hip_atomic_load(p, __ATOMIC_RELAXED, __HIP_MEMORY_SCOPE_AGENT) != want)
      __builtin_amdgcn_s_sleep(16);
  }
  __syncthreads();
  __builtin_amdgcn_fence(__ATOMIC_ACQUIRE, "agent");
}
__device__ __forceinline__ void signal_add(int* p){
  __syncthreads();                                     // all block stores ordered first
  if (threadIdx.x == 0)
    __hip_atomic_fetch_add(p, 1, __ATOMIC_RELEASE, __HIP_MEMORY_SCOPE_AGENT);
}

// ---------- init: zero out + flags ----------
__global__ void k_init(float* __restrict__ out, long n, int* __restrict__ flags, int nf){
  long i = (long)blockIdx.x * blockDim.x + threadIdx.x;
  long st = (long)gridDim.x * blockDim.x;
  for (long v = i; v < n; v += st) out[v] = 0.f;
  for (long v = i; v < nf; v += st) flags[v] = 0;
}

// ---------- fp32 -> bf16 (zero-padded tail) ----------
__global__ void k_conv(const float* __restrict__ in, u16* __restrict__ outp,
                       long nValid, long nTotal){
  long i = (long)blockIdx.x * blockDim.x + threadIdx.x;
  long stride = (long)gridDim.x * blockDim.x;
  long n8 = nTotal >> 3;
  for (long v = i; v < n8; v += stride){
    long base = v << 3;
    uint4 o;
    if (base < nValid){
      const float4 f0 = *(const float4*)(in + base);
      const float4 f1 = *(const float4*)(in + base + 4);
      o.x = f2bf2(f0.x, f0.y); o.y = f2bf2(f0.z, f0.w);
      o.z = f2bf2(f1.x, f1.y); o.w = f2bf2(f1.z, f1.w);
    } else {
      o.x = 0u; o.y = 0u; o.z = 0u; o.w = 0u;
    }
    *(uint4*)(outp + base) = o;
  }
}

// ---------- router: logits + softmax (fp32, one wave per token) ----------
__global__ void k_router(const float* __restrict__ x, const float* __restrict__ Wr,
                         const float* __restrict__ br, float* __restrict__ probs){
  int w = (int)((blockIdx.x * (long)blockDim.x + threadIdx.x) >> 6);
  int lane = threadIdx.x & 63;
  if (w >= (int)T_TOK) return;
  const float* xr = x + (long)w * D_DIM;
  float l[8];
#pragma unroll
  for (int e = 0; e < 8; ++e) l[e] = 0.f;
#pragma unroll
  for (int c = 0; c < 3; ++c){
    const float4 xv = *(const float4*)(xr + c*256 + lane*4);
#pragma unroll
    for (int e = 0; e < 8; ++e){
      const float4 wv = *(const float4*)(Wr + (long)e*D_DIM + c*256 + lane*4);
      l[e] += xv.x*wv.x + xv.y*wv.y + xv.z*wv.z + xv.w*wv.w;
    }
  }
#pragma unroll
  for (int e = 0; e < 8; ++e){
#pragma unroll
    for (int off = 32; off > 0; off >>= 1) l[e] += __shfl_xor(l[e], off);
    l[e] += br[e];
  }
  float m = l[0];
#pragma unroll
  for (int e = 1; e < 8; ++e) m = fmaxf(m, l[e]);
  float s = 0.f;
#pragma unroll
  for (int e = 0; e < 8; ++e){ l[e] = __expf(l[e] - m); s += l[e]; }
  float inv = 1.f / s;
  if (lane == 0){
    float4 p0 = { l[0]*inv, l[1]*inv, l[2]*inv, l[3]*inv };
    float4 p1 = { l[4]*inv, l[5]*inv, l[6]*inv, l[7]*inv };
    *(float4*)(probs + (long)w*8)     = p0;
    *(float4*)(probs + (long)w*8 + 4) = p1;
  }
}

// ---------- 128x128 GEMM body (m97 structure, proven r10) ----------
__device__ __forceinline__ void gemm128(const u16* __restrict__ Ag, long lda,
                                        const u16* __restrict__ Bg, long ldb,
                                        int NT, u16* As, u16* Bs,
                                        int tid, f32x4 (&acc)[4][4]){
  const int l  = tid & 63, w = tid >> 6;
  const int wr = w >> 1,  wc = w & 1;
  const int g4 = l >> 4,  ln = l & 15;

  const int rw = l >> 3;
  const int c8 = (l & 7) ^ rw;
  const u16* pA = Ag + (long)(w*8 + rw) * lda + c8*8;
  const u16* pB = Bg + (long)(w*8 + rw) * ldb + c8*8;
  const long sA = 32 * lda, sB = 32 * ldb;
  u16* dA = As + w*512;
  u16* dB = Bs + w*512;

  int offA[2][4], offB[2][4];
#pragma unroll
  for (int kk = 0; kk < 2; ++kk)
#pragma unroll
    for (int i = 0; i < 4; ++i){
      const int co = (((kk<<2) | g4) ^ (ln & 7)) << 3;
      offA[kk][i] = (wr*64 + i*16 + ln)*64 + co;
      offB[kk][i] = (wc*64 + i*16 + ln)*64 + co;
    }

  for (int kt = 0; kt < NT; ++kt){
    gload_lds16(pA,        dA);
    gload_lds16(pA +   sA, dA + 2048);
    gload_lds16(pA + 2*sA, dA + 4096);
    gload_lds16(pA + 3*sA, dA + 6144);
    gload_lds16(pB,        dB);
    gload_lds16(pB +   sB, dB + 2048);
    gload_lds16(pB + 2*sB, dB + 4096);
    gload_lds16(pB + 3*sB, dB + 6144);
    pA += 64; pB += 64;
    __syncthreads();

    s16x8 a0[4], b0[4], a1[4], b1[4];
#pragma unroll
    for (int i = 0; i < 4; ++i) a0[i] = *(const s16x8*)(As + offA[0][i]);
#pragma unroll
    for (int i = 0; i < 4; ++i) b0[i] = *(const s16x8*)(Bs + offB[0][i]);
#pragma unroll
    for (int mi = 0; mi < 4; ++mi)
#pragma unroll
      for (int ni = 0; ni < 4; ++ni)
        acc[mi][ni] = __builtin_amdgcn_mfma_f32_16x16x32_bf16(a0[mi], b0[ni], acc[mi][ni], 0, 0, 0);
#pragma unroll
    for (int i = 0; i < 4; ++i) a1[i] = *(const s16x8*)(As + offA[1][i]);
#pragma unroll
    for (int i = 0; i < 4; ++i) b1[i] = *(const s16x8*)(Bs + offB[1][i]);
#pragma unroll
    for (int mi = 0; mi < 4; ++mi)
#pragma unroll
      for (int ni = 0; ni < 4; ++ni)
        acc[mi][ni] = __builtin_amdgcn_mfma_f32_16x16x32_bf16(a1[mi], b1[ni], acc[mi][ni], 0, 0, 0);
    __syncthreads();
  }
}

// ---------- mega dispatch: all experts, g1 + g2, flag-synced pool ----------
__global__ __launch_bounds__(256) void k_mega(const u16* __restrict__ xb,
                                              const u16* __restrict__ w1b,
                                              const float* __restrict__ b1,
                                              const u16* __restrict__ w2b,
                                              const float* __restrict__ b2,
                                              const float* __restrict__ probs,
                                              float* __restrict__ out,
                                              u16* __restrict__ hbA,
                                              u16* __restrict__ hbB,
                                              int* __restrict__ flags){
  __shared__ alignas(16) u16 As[8192];
  __shared__ alignas(16) u16 Bs[8192];
  const int tid = threadIdx.x;
  const int l  = tid & 63, w = tid >> 6;
  const int wr = w >> 1,  wc = w & 1;
  const int g4 = l >> 4,  ln = l & 15;

  const int e = (int)blockIdx.x / PE;
  const int r = (int)blockIdx.x % PE;
  if (r >= 3870) return;
  int* cnt    = flags;        // [16] g1 blocks done per (e,half)
  int* gdone  = flags + 16;   // [16] g2 blocks done per (e,half)
  int* ticket = flags + 32;   // [774] out-tile expert turn

  int role, half, wg;
  if      (r < G1A)            { role = 1; half = 0; wg = xcd_chunk(r, G1A); }
  else if (r < G1A+G2A)        { role = 2; half = 0; wg = xcd_chunk(r - G1A, G2A); }
  else if (r < G1A+G2A+G1B)    { role = 1; half = 1; wg = xcd_chunk(r - G1A - G2A, G1B); }
  else                         { role = 2; half = 1; wg = xcd_chunk(r - G1A - G2A - G1B, G2B); }

  f32x4 acc[4][4] = {};

  if (role == 1){
    // ---- g1: hb(half) = quick_gelu(xb·W1[e]^T + b1) ; x-fastest chunk ----
    const int mt1 = half ? 65 : 64;
    const int t01 = half ? 8192 : 0;
    u16* hbW = half ? hbB : hbA;
    const int tx = wg % mt1, ty = wg / mt1;
    const int m0 = tx << 7, n0 = ty << 7;
    // back-pressure: hb(half) still being read by g2(e-1,half)
    if (e > 0) spin_ge(&gdone[(e-1)*2 + half], half ? G2B : G2A);
    gemm128(xb + (long)(t01 + m0) * D_DIM, D_DIM,
            w1b + ((long)e * H_DIM + n0) * D_DIM, D_DIM,
            12, As, Bs, tid, acc);
    float bias[4];
#pragma unroll
    for (int ni = 0; ni < 4; ++ni) bias[ni] = b1[(long)e*H_DIM + n0 + wc*64 + ni*16 + ln];
#pragma unroll
    for (int mi = 0; mi < 4; ++mi){
#pragma unroll
      for (int j = 0; j < 4; ++j){
        const int rr = m0 + wr*64 + mi*16 + g4*4 + j;     // half-local row
        u16* dst = hbW + (long)rr * H_DIM + n0 + wc*64;
#pragma unroll
        for (int ni = 0; ni < 4; ++ni){
          const float v  = acc[mi][ni][j] + bias[ni];
          const float gl = v / (1.0f + __expf(-1.702f * v));  // quick_gelu
          dst[ni*16 + ln] = f2bf(gl);
        }
      }
    }
    signal_add(&cnt[e*2 + half]);
  } else {
    // ---- g2: out += probs[:,e]*(hb·W2[e]^T + b2) ; y-fastest chunk ----
    const int mt2 = half ? 65 : 64;
    const int t02 = half ? 8192 : 0;
    const u16* hbR = half ? hbB : hbA;
    const int tx = wg / 6, ty = wg % 6;
    const int m0 = tx << 7, n0 = ty << 7;
    spin_ge(&cnt[e*2 + half], half ? G1B : G1A);          // wait g1(e,half)
    gemm128(hbR + (long)m0 * H_DIM, H_DIM,
            w2b + ((long)e * D_DIM + n0) * H_DIM, H_DIM,
            48, As, Bs, tid, acc);
    signal_add(&gdone[e*2 + half]);                        // hb reads complete
    float bias[4];
#pragma unroll
    for (int ni = 0; ni < 4; ++ni) bias[ni] = b2[(long)e*D_DIM + n0 + wc*64 + ni*16 + ln];
    // per-out-tile ticket: serialize experts on this tile (tile-parallel)
    const int tk = (half ? G2A : 0) + tx*6 + ty;
    spin_eq(&ticket[tk], e);
#pragma unroll
    for (int mi = 0; mi < 4; ++mi){
#pragma unroll
      for (int j = 0; j < 4; ++j){
        const int gt = t02 + m0 + wr*64 + mi*16 + g4*4 + j;
        if (gt < (int)T_TOK){
          const float p = probs[(long)gt*8 + e];
          float* dst = out + (long)gt * D_DIM + n0 + wc*64;
#pragma unroll
          for (int ni = 0; ni < 4; ++ni)
            dst[ni*16 + ln] += p * (acc[mi][ni][j] + bias[ni]);
        }
      }
    }
    __syncthreads();
    if (tid == 0)
      __hip_atomic_store(&ticket[tk], e + 1, __ATOMIC_RELEASE, __HIP_MEMORY_SCOPE_AGENT);
  }
}

// ---------- host ----------
extern "C" void kernel_launch(void* const* d_in, const int* in_sizes, int n_in,
                              void* d_out, int out_size, void* d_ws, size_t ws_size,
                              hipStream_t stream){
  const float* x  = (const float*)d_in[0];
  const float* W1 = (const float*)d_in[1];
  const float* b1 = (const float*)d_in[2];
  const float* W2 = (const float*)d_in[3];
  const float* b2 = (const float*)d_in[4];
  const float* Wr = (const float*)d_in[5];
  const float* br = (const float*)d_in[6];
  float* out = (float*)d_out;

  char* ws = (char*)d_ws;
  size_t off = 0;
  auto carve = [&](size_t bytes)->void*{
    void* p = ws + off; off += (bytes + 255) & ~(size_t)255; return p;
  };
  u16*   xb    = (u16*)  carve((size_t)M_PAD * D_DIM * 2);
  u16*   w1b   = (u16*)  carve((size_t)E_NUM * H_DIM * D_DIM * 2);
  u16*   w2b   = (u16*)  carve((size_t)E_NUM * D_DIM * H_DIM * 2);
  float* probs = (float*)carve((size_t)T_TOK * E_NUM * 4);
  u16*   hbA   = (u16*)  carve((size_t)8192 * H_DIM * 2);   // tokens [0, 8192)
  u16*   hbB   = (u16*)  carve((size_t)8320 * H_DIM * 2);   // tokens [8192, 16512)
  int*   flags = (int*)  carve(4096);

  // init (out + flags), conversions, router — all stream-ordered before mega
  k_init<<<dim3(1024), dim3(256), 0, stream>>>(out, (long)out_size, flags, 1024);
  k_conv<<<dim3(2048), dim3(256), 0, stream>>>(x,  xb,  T_TOK*D_DIM, M_PAD*D_DIM);
  k_conv<<<dim3(2048), dim3(256), 0, stream>>>(W1, w1b, E_NUM*H_DIM*D_DIM, E_NUM*H_DIM*D_DIM);
  k_conv<<<dim3(2048), dim3(256), 0, stream>>>(W2, w2b, E_NUM*D_DIM*H_DIM, E_NUM*D_DIM*H_DIM);
  k_router<<<dim3(4112), dim3(256), 0, stream>>>(x, Wr, br, probs);

  // one mega dispatch: 8 experts x [g1A | g2A | g1B | g2B]
  k_mega<<<dim3((unsigned)(E_NUM * PE)), dim3(256), 0, stream>>>(
      xb, w1b, b1, w2b, b2, probs, out, hbA, hbB, flags);
}

// Round 12
// 2350.730 us; speedup vs baseline: 1.8170x; 1.8170x over previous
//
#include <hip/hip_runtime.h>

typedef unsigned short u16;
typedef float f32x4 __attribute__((ext_vector_type(4)));
typedef short s16x8 __attribute__((ext_vector_type(8)));

#define T_TOK   16448L   // 257*64
#define D_DIM   768L
#define H_DIM   3072L
#define E_NUM   8L
#define M_PAD   16512L   // halves: A=8192 rows (64 tiles), B=8320 rows (65 tiles)

// ---------- helpers ----------
__device__ __forceinline__ u16 f2bf(float f){
  unsigned u = __float_as_uint(f);
  u = u + 0x7FFFu + ((u >> 16) & 1u);          // RNE
  return (u16)(u >> 16);
}
__device__ __forceinline__ unsigned f2bf2(float a, float b){
  return (unsigned)f2bf(a) | ((unsigned)f2bf(b) << 16);
}

__device__ __forceinline__ void gload_lds16(const u16* g, u16* s){
  __builtin_amdgcn_global_load_lds((const __attribute__((address_space(1))) void*)g,
                                   (__attribute__((address_space(3))) void*)s,
                                   16, 0, 0);
}

// bijective XCD chunking (m204)
__device__ __forceinline__ int xcd_chunk(int idx, int n){
  const int q = n >> 3, r = n & 7, x = idx & 7;
  return (x < r ? x*(q+1) : r*(q+1) + (x-r)*q) + (idx >> 3);
}

// ---------- fp32 -> bf16 (zero-padded tail) ----------
__global__ void k_conv(const float* __restrict__ in, u16* __restrict__ outp,
                       long nValid, long nTotal){
  long i = (long)blockIdx.x * blockDim.x + threadIdx.x;
  long stride = (long)gridDim.x * blockDim.x;
  long n8 = nTotal >> 3;
  for (long v = i; v < n8; v += stride){
    long base = v << 3;
    uint4 o;
    if (base < nValid){
      const float4 f0 = *(const float4*)(in + base);
      const float4 f1 = *(const float4*)(in + base + 4);
      o.x = f2bf2(f0.x, f0.y); o.y = f2bf2(f0.z, f0.w);
      o.z = f2bf2(f1.x, f1.y); o.w = f2bf2(f1.z, f1.w);
    } else {
      o.x = 0u; o.y = 0u; o.z = 0u; o.w = 0u;
    }
    *(uint4*)(outp + base) = o;
  }
}

// ---------- router: logits + softmax (fp32, one wave per token) ----------
__global__ void k_router(const float* __restrict__ x, const float* __restrict__ Wr,
                         const float* __restrict__ br, float* __restrict__ probs){
  int w = (int)((blockIdx.x * (long)blockDim.x + threadIdx.x) >> 6);
  int lane = threadIdx.x & 63;
  if (w >= (int)T_TOK) return;
  const float* xr = x + (long)w * D_DIM;
  float l[8];
#pragma unroll
  for (int e = 0; e < 8; ++e) l[e] = 0.f;
#pragma unroll
  for (int c = 0; c < 3; ++c){
    const float4 xv = *(const float4*)(xr + c*256 + lane*4);
#pragma unroll
    for (int e = 0; e < 8; ++e){
      const float4 wv = *(const float4*)(Wr + (long)e*D_DIM + c*256 + lane*4);
      l[e] += xv.x*wv.x + xv.y*wv.y + xv.z*wv.z + xv.w*wv.w;
    }
  }
#pragma unroll
  for (int e = 0; e < 8; ++e){
#pragma unroll
    for (int off = 32; off > 0; off >>= 1) l[e] += __shfl_xor(l[e], off);
    l[e] += br[e];
  }
  float m = l[0];
#pragma unroll
  for (int e = 1; e < 8; ++e) m = fmaxf(m, l[e]);
  float s = 0.f;
#pragma unroll
  for (int e = 0; e < 8; ++e){ l[e] = __expf(l[e] - m); s += l[e]; }
  float inv = 1.f / s;
  if (lane == 0){
    float4 p0 = { l[0]*inv, l[1]*inv, l[2]*inv, l[3]*inv };
    float4 p1 = { l[4]*inv, l[5]*inv, l[6]*inv, l[7]*inv };
    *(float4*)(probs + (long)w*8)     = p0;
    *(float4*)(probs + (long)w*8 + 4) = p1;
  }
}

// ---------- final reduce: out += part1 ----------
__global__ void k_reduce(float* __restrict__ out, const float* __restrict__ part1,
                         long n4){
  long i = (long)blockIdx.x * blockDim.x + threadIdx.x;
  long st = (long)gridDim.x * blockDim.x;
  for (long v = i; v < n4; v += st){
    float4 a = *(const float4*)(out + (v<<2));
    const float4 b = *(const float4*)(part1 + (v<<2));
    a.x += b.x; a.y += b.y; a.z += b.z; a.w += b.w;
    *(float4*)(out + (v<<2)) = a;
  }
}

// ---------- 128x128 GEMM body (m97 structure, proven r10) ----------
__device__ __forceinline__ void gemm128(const u16* __restrict__ Ag, long lda,
                                        const u16* __restrict__ Bg, long ldb,
                                        int NT, u16* As, u16* Bs,
                                        int tid, f32x4 (&acc)[4][4]){
  const int l  = tid & 63, w = tid >> 6;
  const int wr = w >> 1,  wc = w & 1;
  const int g4 = l >> 4,  ln = l & 15;

  const int rw = l >> 3;
  const int c8 = (l & 7) ^ rw;
  const u16* pA = Ag + (long)(w*8 + rw) * lda + c8*8;
  const u16* pB = Bg + (long)(w*8 + rw) * ldb + c8*8;
  const long sA = 32 * lda, sB = 32 * ldb;
  u16* dA = As + w*512;
  u16* dB = Bs + w*512;

  int offA[2][4], offB[2][4];
#pragma unroll
  for (int kk = 0; kk < 2; ++kk)
#pragma unroll
    for (int i = 0; i < 4; ++i){
      const int co = (((kk<<2) | g4) ^ (ln & 7)) << 3;
      offA[kk][i] = (wr*64 + i*16 + ln)*64 + co;
      offB[kk][i] = (wc*64 + i*16 + ln)*64 + co;
    }

  for (int kt = 0; kt < NT; ++kt){
    gload_lds16(pA,        dA);
    gload_lds16(pA +   sA, dA + 2048);
    gload_lds16(pA + 2*sA, dA + 4096);
    gload_lds16(pA + 3*sA, dA + 6144);
    gload_lds16(pB,        dB);
    gload_lds16(pB +   sB, dB + 2048);
    gload_lds16(pB + 2*sB, dB + 4096);
    gload_lds16(pB + 3*sB, dB + 6144);
    pA += 64; pB += 64;
    __syncthreads();

    s16x8 a0[4], b0[4], a1[4], b1[4];
#pragma unroll
    for (int i = 0; i < 4; ++i) a0[i] = *(const s16x8*)(As + offA[0][i]);
#pragma unroll
    for (int i = 0; i < 4; ++i) b0[i] = *(const s16x8*)(Bs + offB[0][i]);
#pragma unroll
    for (int mi = 0; mi < 4; ++mi)
#pragma unroll
      for (int ni = 0; ni < 4; ++ni)
        acc[mi][ni] = __builtin_amdgcn_mfma_f32_16x16x32_bf16(a0[mi], b0[ni], acc[mi][ni], 0, 0, 0);
#pragma unroll
    for (int i = 0; i < 4; ++i) a1[i] = *(const s16x8*)(As + offA[1][i]);
#pragma unroll
    for (int i = 0; i < 4; ++i) b1[i] = *(const s16x8*)(Bs + offB[1][i]);
#pragma unroll
    for (int mi = 0; mi < 4; ++mi)
#pragma unroll
      for (int ni = 0; ni < 4; ++ni)
        acc[mi][ni] = __builtin_amdgcn_mfma_f32_16x16x32_bf16(a1[mi], b1[ni], acc[mi][ni], 0, 0, 0);
    __syncthreads();
  }
}

// ---------- paired dispatch: split-K g2(e2, half X) + g1(e1, half Y) ----------
// g2 block = (split sp, m-tile, n-tile): K-range [sp*1536, sp*1536+1536), 24 K-tiles.
// sp==0 accumulates p*(acc+b2) into out; sp==1 accumulates p*acc into part1.
// Both use e==0-store / else-RMW (deterministic; one block per tile per dispatch).
__global__ __launch_bounds__(256) void k_pair(const u16* __restrict__ xb,
                                              const u16* __restrict__ w1b,
                                              const float* __restrict__ b1,
                                              const u16* __restrict__ w2b,
                                              const float* __restrict__ b2,
                                              const float* __restrict__ probs,
                                              float* __restrict__ out,
                                              float* __restrict__ part1,
                                              const u16* __restrict__ hbR,
                                              u16* __restrict__ hbW,
                                              int e2, int t02, int mt2,
                                              int e1, int t01, int mt1, int n2){
  __shared__ alignas(16) u16 As[8192];
  __shared__ alignas(16) u16 Bs[8192];
  const int tid = threadIdx.x;
  const int l  = tid & 63, w = tid >> 6;
  const int wr = w >> 1,  wc = w & 1;
  const int g4 = l >> 4,  ln = l & 15;
  const int bx = (int)blockIdx.x;
  f32x4 acc[4][4] = {};

  if (bx < n2){
    // ---- g2 split-K: decode (sp, tx, ty); y-fastest in tile for A-panel reuse ----
    const int wg  = xcd_chunk(bx, n2);
    const int per = mt2 * 6;
    const int sp  = wg / per;
    const int rem = wg % per;
    const int tx = rem / 6, ty = rem % 6;
    const int m0 = tx << 7, n0 = ty << 7;
    gemm128(hbR + (long)m0 * H_DIM + sp*1536, H_DIM,
            w2b + ((long)e2 * D_DIM + n0) * H_DIM + sp*1536, H_DIM,
            24, As, Bs, tid, acc);
    float bias[4];
#pragma unroll
    for (int ni = 0; ni < 4; ++ni)
      bias[ni] = sp ? 0.f : b2[(long)e2*D_DIM + n0 + wc*64 + ni*16 + ln];
    float* dstBuf = sp ? part1 : out;
#pragma unroll
    for (int mi = 0; mi < 4; ++mi){
#pragma unroll
      for (int j = 0; j < 4; ++j){
        const int gt = t02 + m0 + wr*64 + mi*16 + g4*4 + j;
        if (gt < (int)T_TOK){
          const float p = probs[(long)gt*8 + e2];
          float* dst = dstBuf + (long)gt * D_DIM + n0 + wc*64;
#pragma unroll
          for (int ni = 0; ni < 4; ++ni){
            const float v = p * (acc[mi][ni][j] + bias[ni]);
            if (e2 == 0) dst[ni*16 + ln] = v;
            else         dst[ni*16 + ln] += v;
          }
        }
      }
    }
  } else {
    // ---- g1: x-fastest chunk (B-panel reuse along chunk) ----
    const int n1 = (int)gridDim.x - n2;
    const int wg = xcd_chunk(bx - n2, n1);
    const int tx = wg % mt1, ty = wg / mt1;
    const int m0 = tx << 7, n0 = ty << 7;
    gemm128(xb + (long)(t01 + m0) * D_DIM, D_DIM,
            w1b + ((long)e1 * H_DIM + n0) * D_DIM, D_DIM,
            12, As, Bs, tid, acc);
    float bias[4];
#pragma unroll
    for (int ni = 0; ni < 4; ++ni) bias[ni] = b1[(long)e1*H_DIM + n0 + wc*64 + ni*16 + ln];
#pragma unroll
    for (int mi = 0; mi < 4; ++mi){
#pragma unroll
      for (int j = 0; j < 4; ++j){
        const int r = m0 + wr*64 + mi*16 + g4*4 + j;      // half-local row
        u16* dst = hbW + (long)r * H_DIM + n0 + wc*64;
#pragma unroll
        for (int ni = 0; ni < 4; ++ni){
          const float v  = acc[mi][ni][j] + bias[ni];
          const float gl = v / (1.0f + __expf(-1.702f * v));  // quick_gelu
          dst[ni*16 + ln] = f2bf(gl);
        }
      }
    }
  }
}

// ---------- host ----------
extern "C" void kernel_launch(void* const* d_in, const int* in_sizes, int n_in,
                              void* d_out, int out_size, void* d_ws, size_t ws_size,
                              hipStream_t stream){
  const float* x  = (const float*)d_in[0];
  const float* W1 = (const float*)d_in[1];
  const float* b1 = (const float*)d_in[2];
  const float* W2 = (const float*)d_in[3];
  const float* b2 = (const float*)d_in[4];
  const float* Wr = (const float*)d_in[5];
  const float* br = (const float*)d_in[6];
  float* out = (float*)d_out;

  char* ws = (char*)d_ws;
  size_t off = 0;
  auto carve = [&](size_t bytes)->void*{
    void* p = ws + off; off += (bytes + 255) & ~(size_t)255; return p;
  };
  u16*   xb    = (u16*)  carve((size_t)M_PAD * D_DIM * 2);
  u16*   w1b   = (u16*)  carve((size_t)E_NUM * H_DIM * D_DIM * 2);
  u16*   w2b   = (u16*)  carve((size_t)E_NUM * D_DIM * H_DIM * 2);
  float* probs = (float*)carve((size_t)T_TOK * E_NUM * 4);
  u16*   hbA   = (u16*)  carve((size_t)8192 * H_DIM * 2);   // tokens [0, 8192)
  u16*   hbB   = (u16*)  carve((size_t)8320 * H_DIM * 2);   // tokens [8192, 16512)
  float* part1 = (float*)carve((size_t)T_TOK * D_DIM * 4);  // split-1 fp32 partial

  // conversions + router
  k_conv<<<dim3(2048), dim3(256), 0, stream>>>(x,  xb,  T_TOK*D_DIM, M_PAD*D_DIM);
  k_conv<<<dim3(2048), dim3(256), 0, stream>>>(W1, w1b, E_NUM*H_DIM*D_DIM, E_NUM*H_DIM*D_DIM);
  k_conv<<<dim3(2048), dim3(256), 0, stream>>>(W2, w2b, E_NUM*D_DIM*H_DIM, E_NUM*D_DIM*H_DIM);
  k_router<<<dim3(4112), dim3(256), 0, stream>>>(x, Wr, br, probs);

  const int MTA = 64, MTB = 65;      // 128-row tile counts per token-half
  const int T0A = 0,  T0B = 8192;

  auto pair = [&](int e2, const u16* hbR, int t02, int mt2,
                  int e1, u16* hbW, int t01, int mt1){
    const int n2 = mt2 * 12;         // 6 n-tiles x 2 K-splits
    const int n1 = mt1 * 24;
    k_pair<<<dim3((unsigned)(n2 + n1)), dim3(256), 0, stream>>>(
        xb, w1b, b1, w2b, b2, probs, out, part1, hbR, hbW,
        e2, t02, mt2, e1, t01, mt1, n2);
  };

  // ping-pong: D0: g1(0,A); D(2e+1): g2(e,A)+g1(e,B); D(2e+2): g2(e,B)+g1(e+1,A); D16: g2(7,B)
  pair(0, nullptr, 0, 0, 0, hbA, T0A, MTA);
  for (int e = 0; e < 8; ++e){
    pair(e, hbA, T0A, MTA, e, hbB, T0B, MTB);
    if (e < 7) pair(e, hbB, T0B, MTB, e + 1, hbA, T0A, MTA);
  }
  pair(7, hbB, T0B, MTB, 0, nullptr, 0, 0);

  // out += part1
  k_reduce<<<dim3(2048), dim3(256), 0, stream>>>(out, part1, (T_TOK * D_DIM) >> 2);
}

// Round 13
// 2101.499 us; speedup vs baseline: 2.0325x; 1.1186x over previous
//
#include <hip/hip_runtime.h>

typedef unsigned short u16;
typedef float f32x4 __attribute__((ext_vector_type(4)));
typedef short s16x8 __attribute__((ext_vector_type(8)));

#define T_TOK   16448L   // 257*64
#define D_DIM   768L
#define H_DIM   3072L
#define E_NUM   8L
#define M_PAD   16640L   // 65*256 ; halves: A=8192 rows (32 tiles), B=8448 rows (33 tiles)

// ---------- helpers ----------
__device__ __forceinline__ u16 f2bf(float f){
  unsigned u = __float_as_uint(f);
  u = u + 0x7FFFu + ((u >> 16) & 1u);          // RNE
  return (u16)(u >> 16);
}
__device__ __forceinline__ unsigned f2bf2(float a, float b){
  return (unsigned)f2bf(a) | ((unsigned)f2bf(b) << 16);
}

__device__ __forceinline__ void gload_lds16(const u16* g, u16* s){
  __builtin_amdgcn_global_load_lds((const __attribute__((address_space(1))) void*)g,
                                   (__attribute__((address_space(3))) void*)s,
                                   16, 0, 0);
}

// bijective XCD chunking (m204)
__device__ __forceinline__ int xcd_chunk(int idx, int n){
  const int q = n >> 3, r = n & 7, x = idx & 7;
  return (x < r ? x*(q+1) : r*(q+1) + (x-r)*q) + (idx >> 3);
}

// ---------- zero-init out ----------
__global__ void k_init(float* __restrict__ out, long n4){
  long i = (long)blockIdx.x * blockDim.x + threadIdx.x;
  long st = (long)gridDim.x * blockDim.x;
  const float4 z = {0.f, 0.f, 0.f, 0.f};
  for (long v = i; v < n4; v += st) *(float4*)(out + (v<<2)) = z;
}

// ---------- fp32 -> bf16 (zero-padded tail) ----------
__global__ void k_conv(const float* __restrict__ in, u16* __restrict__ outp,
                       long nValid, long nTotal){
  long i = (long)blockIdx.x * blockDim.x + threadIdx.x;
  long stride = (long)gridDim.x * blockDim.x;
  long n8 = nTotal >> 3;
  for (long v = i; v < n8; v += stride){
    long base = v << 3;
    uint4 o;
    if (base < nValid){
      const float4 f0 = *(const float4*)(in + base);
      const float4 f1 = *(const float4*)(in + base + 4);
      o.x = f2bf2(f0.x, f0.y); o.y = f2bf2(f0.z, f0.w);
      o.z = f2bf2(f1.x, f1.y); o.w = f2bf2(f1.z, f1.w);
    } else {
      o.x = 0u; o.y = 0u; o.z = 0u; o.w = 0u;
    }
    *(uint4*)(outp + base) = o;
  }
}

// ---------- router: logits + softmax (fp32, one wave per token) ----------
__global__ void k_router(const float* __restrict__ x, const float* __restrict__ Wr,
                         const float* __restrict__ br, float* __restrict__ probs){
  int w = (int)((blockIdx.x * (long)blockDim.x + threadIdx.x) >> 6);
  int lane = threadIdx.x & 63;
  if (w >= (int)T_TOK) return;
  const float* xr = x + (long)w * D_DIM;
  float l[8];
#pragma unroll
  for (int e = 0; e < 8; ++e) l[e] = 0.f;
#pragma unroll
  for (int c = 0; c < 3; ++c){
    const float4 xv = *(const float4*)(xr + c*256 + lane*4);
#pragma unroll
    for (int e = 0; e < 8; ++e){
      const float4 wv = *(const float4*)(Wr + (long)e*D_DIM + c*256 + lane*4);
      l[e] += xv.x*wv.x + xv.y*wv.y + xv.z*wv.z + xv.w*wv.w;
    }
  }
#pragma unroll
  for (int e = 0; e < 8; ++e){
#pragma unroll
    for (int off = 32; off > 0; off >>= 1) l[e] += __shfl_xor(l[e], off);
    l[e] += br[e];
  }
  float m = l[0];
#pragma unroll
  for (int e = 1; e < 8; ++e) m = fmaxf(m, l[e]);
  float s = 0.f;
#pragma unroll
  for (int e = 0; e < 8; ++e){ l[e] = __expf(l[e] - m); s += l[e]; }
  float inv = 1.f / s;
  if (lane == 0){
    float4 p0 = { l[0]*inv, l[1]*inv, l[2]*inv, l[3]*inv };
    float4 p1 = { l[4]*inv, l[5]*inv, l[6]*inv, l[7]*inv };
    *(float4*)(probs + (long)w*8)     = p0;
    *(float4*)(probs + (long)w*8 + 4) = p1;
  }
}

#define FENCE()  __builtin_amdgcn_sched_barrier(0)
#define BAR()    do{ FENCE(); __builtin_amdgcn_s_barrier(); FENCE(); }while(0)
#define LGK0()   do{ asm volatile("s_waitcnt lgkmcnt(0)" ::: "memory"); FENCE(); }while(0)

// read one 16-row MFMA fragment: rows rbase..rbase+15, logical k-chunk c (0..7)
__device__ __forceinline__ s16x8 ld_frag(const u16* S, int rbase, int c, int ln){
  const int r = rbase + ln;
  return *(const s16x8*)(S + (r << 6) + ((c ^ (r & 7)) << 3));
}

// ---------- 256x256 GEMM, BK=64, 4-phase fine interleave (r9, fastest) ----------
__device__ __forceinline__ void gemm256(const u16* __restrict__ Ag, long lda,
                                        const u16* __restrict__ Bg, long ldb,
                                        int NT, u16* lds, int tid,
                                        f32x4 (&acc)[8][4]){
  const int l  = tid & 63, w = tid >> 6;
  const int wr = w >> 2,  wc = w & 3;
  const int g4 = l >> 4,  ln = l & 15;

  const int rw = l >> 3;
  const int c8 = (l & 7) ^ rw;
  const u16* gA = Ag + (long)(w*8 + rw) * lda + c8*8;
  const u16* gB = Bg + (long)(w*8 + rw) * ldb + c8*8;
  u16* s0 = lds + w*512;
#define SA(par,T,rnd) gload_lds16(gA + (long)(T)*64 + (long)(rnd)*64*lda, s0 + (par)*32768 + (rnd)*4096)
#define SB(par,T,rnd) gload_lds16(gB + (long)(T)*64 + (long)(rnd)*64*ldb, s0 + (par)*32768 + 16384 + (rnd)*4096)

  // prologue: t0 full (8 loads), t1 early-half (4) -> wait t0 (t1's 4 in flight)
#pragma unroll
  for (int i = 0; i < 4; ++i) SA(0,0,i);
#pragma unroll
  for (int i = 0; i < 4; ++i) SB(0,0,i);
  SA(1,1,0); SB(1,1,0); SA(1,1,2); SB(1,1,1);
  FENCE();
  asm volatile("s_waitcnt vmcnt(4)" ::: "memory");
  BAR();

  for (int kt = 0; kt < NT; ++kt){
    const int par = kt & 1, oth = par ^ 1;
    const u16* As = lds + par * 32768;
    const u16* Bs = As + 16384;
    const bool st1 = (kt + 1 < NT), st2 = (kt + 2 < NT);
    s16x8 aL[4], aH[4], b0[4], b1[4];

    // ---- ph0 ----
#pragma unroll
    for (int ni = 0; ni < 4; ++ni) b0[ni] = ld_frag(Bs, wc*64 + ni*16, g4, ln);
#pragma unroll
    for (int mi = 0; mi < 4; ++mi) aL[mi] = ld_frag(As, wr*128 + mi*16, g4, ln);
    if (st1){ SA(oth, kt+1, 1); SB(oth, kt+1, 2); }
    BAR(); LGK0();
    __builtin_amdgcn_s_setprio(1);
#pragma unroll
    for (int mi = 0; mi < 4; ++mi)
#pragma unroll
      for (int ni = 0; ni < 4; ++ni)
        acc[mi][ni] = __builtin_amdgcn_mfma_f32_16x16x32_bf16(aL[mi], b0[ni], acc[mi][ni], 0, 0, 0);
    __builtin_amdgcn_s_setprio(0);
    BAR();

    // ---- ph1 ----
#pragma unroll
    for (int ni = 0; ni < 4; ++ni) b1[ni] = ld_frag(Bs, wc*64 + ni*16, 4 + g4, ln);
#pragma unroll
    for (int mi = 0; mi < 4; ++mi) aL[mi] = ld_frag(As, wr*128 + mi*16, 4 + g4, ln);
    if (st1){ SA(oth, kt+1, 3); SB(oth, kt+1, 3); }
    BAR(); LGK0();
    __builtin_amdgcn_s_setprio(1);
#pragma unroll
    for (int mi = 0; mi < 4; ++mi)
#pragma unroll
      for (int ni = 0; ni < 4; ++ni)
        acc[mi][ni] = __builtin_amdgcn_mfma_f32_16x16x32_bf16(aL[mi], b1[ni], acc[mi][ni], 0, 0, 0);
    __builtin_amdgcn_s_setprio(0);
    BAR();

    // ---- ph2 ----
#pragma unroll
    for (int mi = 0; mi < 4; ++mi) aH[mi] = ld_frag(As, wr*128 + 64 + mi*16, g4, ln);
    if (st2){ SA(par, kt+2, 0); SB(par, kt+2, 0); }
    BAR(); LGK0();
    __builtin_amdgcn_s_setprio(1);
#pragma unroll
    for (int mi = 0; mi < 4; ++mi)
#pragma unroll
      for (int ni = 0; ni < 4; ++ni)
        acc[mi+4][ni] = __builtin_amdgcn_mfma_f32_16x16x32_bf16(aH[mi], b0[ni], acc[mi+4][ni], 0, 0, 0);
    __builtin_amdgcn_s_setprio(0);
    BAR();

    // ---- ph3 + boundary ----
#pragma unroll
    for (int mi = 0; mi < 4; ++mi) aH[mi] = ld_frag(As, wr*128 + 64 + mi*16, 4 + g4, ln);
    if (st2){ SA(par, kt+2, 2); SB(par, kt+2, 1); }
    BAR(); LGK0();
    __builtin_amdgcn_s_setprio(1);
#pragma unroll
    for (int mi = 0; mi < 4; ++mi)
#pragma unroll
      for (int ni = 0; ni < 4; ++ni)
        acc[mi+4][ni] = __builtin_amdgcn_mfma_f32_16x16x32_bf16(aH[mi], b1[ni], acc[mi+4][ni], 0, 0, 0);
    __builtin_amdgcn_s_setprio(0);

    if (st1){
      FENCE();
      if (st2) asm volatile("s_waitcnt vmcnt(4)" ::: "memory");
      else     asm volatile("s_waitcnt vmcnt(0)" ::: "memory");
      BAR();
    }
  }
#undef SA
#undef SB
}

// ---------- paired dispatch: split-K g2(e2, half X) + g1(e1, other half) ----------
// g2 block = (tx, sp, ty): K-range [sp*1536, sp*1536+1536), 24 K-tiles.
// All g2 output via atomicAdd into pre-zeroed out; bias added by sp==0 only.
__global__ __launch_bounds__(512, 2) void k_pair(const u16* __restrict__ xb,
                                                 const u16* __restrict__ w1b,
                                                 const float* __restrict__ b1,
                                                 const u16* __restrict__ w2b,
                                                 const float* __restrict__ b2,
                                                 const float* __restrict__ probs,
                                                 float* __restrict__ out,
                                                 const u16* __restrict__ hbR,
                                                 u16* __restrict__ hbW,
                                                 int e2, int t02,
                                                 int e1, int t01, int mt1, int n2){
  __shared__ alignas(16) u16 lds[65536];   // 128 KiB: 2 bufs x (A | B)
  const int tid = threadIdx.x;
  const int l  = tid & 63, w = tid >> 6;
  const int wr = w >> 2,  wc = w & 3;
  const int g4 = l >> 4,  ln = l & 15;
  const int bx = (int)blockIdx.x;
  f32x4 acc[8][4] = {};

  if (bx < n2){
    // ---- g2 split-K: wg = (tx*2 + sp)*3 + ty (A-panel + splits adjacent) ----
    const int wg = xcd_chunk(bx, n2);
    const int ty = wg % 3;
    const int sp = (wg / 3) & 1;
    const int tx = wg / 6;
    const int m0 = tx << 8, n0 = ty << 8;
    gemm256(hbR + (long)m0 * H_DIM + sp*1536, H_DIM,
            w2b + ((long)e2 * D_DIM + n0) * H_DIM + sp*1536, H_DIM,
            24, lds, tid, acc);
    float bias[4];
#pragma unroll
    for (int ni = 0; ni < 4; ++ni)
      bias[ni] = sp ? 0.f : b2[(long)e2*D_DIM + n0 + wc*64 + ni*16 + ln];
#pragma unroll
    for (int mi = 0; mi < 8; ++mi){
#pragma unroll
      for (int j = 0; j < 4; ++j){
        const int gt = t02 + m0 + wr*128 + mi*16 + g4*4 + j;
        if (gt < (int)T_TOK){
          const float p = probs[(long)gt*8 + e2];
          float* dst = out + (long)gt * D_DIM + n0 + wc*64;
#pragma unroll
          for (int ni = 0; ni < 4; ++ni)
            atomicAdd(&dst[ni*16 + ln], p * (acc[mi][ni][j] + bias[ni]));
        }
      }
    }
  } else {
    // ---- g1: x-fastest chunk (B-panel reuse along chunk) ----
    const int n1 = (int)gridDim.x - n2;
    const int wg = xcd_chunk(bx - n2, n1);
    const int tx = wg % mt1, ty = wg / mt1;
    const int m0 = tx << 8, n0 = ty << 8;
    gemm256(xb + (long)(t01 + m0) * D_DIM, D_DIM,
            w1b + ((long)e1 * H_DIM + n0) * D_DIM, D_DIM,
            12, lds, tid, acc);
    float bias[4];
#pragma unroll
    for (int ni = 0; ni < 4; ++ni) bias[ni] = b1[(long)e1*H_DIM + n0 + wc*64 + ni*16 + ln];
#pragma unroll
    for (int mi = 0; mi < 8; ++mi){
#pragma unroll
      for (int j = 0; j < 4; ++j){
        const int r = m0 + wr*128 + mi*16 + g4*4 + j;     // half-local row
        u16* dst = hbW + (long)r * H_DIM + n0 + wc*64;
#pragma unroll
        for (int ni = 0; ni < 4; ++ni){
          const float v  = acc[mi][ni][j] + bias[ni];
          const float gl = v / (1.0f + __expf(-1.702f * v));  // quick_gelu
          dst[ni*16 + ln] = f2bf(gl);
        }
      }
    }
  }
}

// ---------- host ----------
extern "C" void kernel_launch(void* const* d_in, const int* in_sizes, int n_in,
                              void* d_out, int out_size, void* d_ws, size_t ws_size,
                              hipStream_t stream){
  const float* x  = (const float*)d_in[0];
  const float* W1 = (const float*)d_in[1];
  const float* b1 = (const float*)d_in[2];
  const float* W2 = (const float*)d_in[3];
  const float* b2 = (const float*)d_in[4];
  const float* Wr = (const float*)d_in[5];
  const float* br = (const float*)d_in[6];
  float* out = (float*)d_out;

  char* ws = (char*)d_ws;
  size_t off = 0;
  auto carve = [&](size_t bytes)->void*{
    void* p = ws + off; off += (bytes + 255) & ~(size_t)255; return p;
  };
  u16*   xb    = (u16*)  carve((size_t)M_PAD * D_DIM * 2);
  u16*   w1b   = (u16*)  carve((size_t)E_NUM * H_DIM * D_DIM * 2);
  u16*   w2b   = (u16*)  carve((size_t)E_NUM * D_DIM * H_DIM * 2);
  float* probs = (float*)carve((size_t)T_TOK * E_NUM * 4);
  u16*   hbA   = (u16*)  carve((size_t)8192 * H_DIM * 2);   // tokens [0, 8192)
  u16*   hbB   = (u16*)  carve((size_t)8448 * H_DIM * 2);   // tokens [8192, 16640)

  // init + conversions + router
  k_init<<<dim3(512), dim3(256), 0, stream>>>(out, (T_TOK * D_DIM) >> 2);
  k_conv<<<dim3(2048), dim3(256), 0, stream>>>(x,  xb,  T_TOK*D_DIM, M_PAD*D_DIM);
  k_conv<<<dim3(2048), dim3(256), 0, stream>>>(W1, w1b, E_NUM*H_DIM*D_DIM, E_NUM*H_DIM*D_DIM);
  k_conv<<<dim3(2048), dim3(256), 0, stream>>>(W2, w2b, E_NUM*D_DIM*H_DIM, E_NUM*D_DIM*H_DIM);
  k_router<<<dim3(4112), dim3(256), 0, stream>>>(x, Wr, br, probs);

  const int MTA = 32, MTB = 33;      // 256-row tile counts per token-half
  const int T0A = 0,  T0B = 8192;

  auto pair = [&](int e2, const u16* hbR, int t02, int mt2,
                  int e1, u16* hbW, int t01, int mt1){
    const int n2 = mt2 * 6;          // 3 n-tiles x 2 K-splits
    const int n1 = mt1 * 12;
    k_pair<<<dim3((unsigned)(n2 + n1)), dim3(512), 0, stream>>>(
        xb, w1b, b1, w2b, b2, probs, out, hbR, hbW,
        e2, t02, e1, t01, mt1, n2);
  };

  // ping-pong: D0: g1(0,A); D(2e+1): g2(e,A)+g1(e,B); D(2e+2): g2(e,B)+g1(e+1,A); D16: g2(7,B)
  pair(0, nullptr, 0, 0, 0, hbA, T0A, MTA);
  for (int e = 0; e < 8; ++e){
    pair(e, hbA, T0A, MTA, e, hbB, T0B, MTB);
    if (e < 7) pair(e, hbB, T0B, MTB, e + 1, hbA, T0A, MTA);
  }
  pair(7, hbB, T0B, MTB, 0, nullptr, 0, 0);
}

// Round 14
// 2013.143 us; speedup vs baseline: 2.1217x; 1.0439x over previous
//
#include <hip/hip_runtime.h>

typedef unsigned short u16;
typedef float f32x4 __attribute__((ext_vector_type(4)));
typedef short s16x8 __attribute__((ext_vector_type(8)));

#define T_TOK   16448L   // 257*64
#define D_DIM   768L
#define H_DIM   3072L
#define E_NUM   8L
#define M_PAD   16640L   // 65*256 ; halves: A=8192 rows (32 tiles), B=8448 rows (33 tiles)

// ---------- helpers ----------
__device__ __forceinline__ u16 f2bf(float f){
  unsigned u = __float_as_uint(f);
  u = u + 0x7FFFu + ((u >> 16) & 1u);          // RNE
  return (u16)(u >> 16);
}
__device__ __forceinline__ unsigned f2bf2(float a, float b){
  return (unsigned)f2bf(a) | ((unsigned)f2bf(b) << 16);
}

__device__ __forceinline__ void gload_lds16(const u16* g, u16* s){
  __builtin_amdgcn_global_load_lds((const __attribute__((address_space(1))) void*)g,
                                   (__attribute__((address_space(3))) void*)s,
                                   16, 0, 0);
}

// bijective XCD chunking (m204)
__device__ __forceinline__ int xcd_chunk(int idx, int n){
  const int q = n >> 3, r = n & 7, x = idx & 7;
  return (x < r ? x*(q+1) : r*(q+1) + (x-r)*q) + (idx >> 3);
}

// ---------- merged prologue: conv x / conv W1 / conv W2 / router in one dispatch ----------
// Role ranges (exact-sized): [0,6240) xb ; [6240,15456) w1b ; [15456,24672) w2b ;
// [24672,28784) router. All four roles independent.
__global__ __launch_bounds__(256) void k_pro(const float* __restrict__ x,
                                             const float* __restrict__ W1,
                                             const float* __restrict__ W2,
                                             const float* __restrict__ Wr,
                                             const float* __restrict__ br,
                                             u16* __restrict__ xb,
                                             u16* __restrict__ w1b,
                                             u16* __restrict__ w2b,
                                             float* __restrict__ probs){
  const int bx = (int)blockIdx.x, tid = threadIdx.x;
  if (bx < 6240){
    // xb: M_PAD*D_DIM = 12,779,520 elems (zero-padded past T_TOK*D_DIM)
    const long base = ((long)bx*256 + tid) << 3;
    uint4 o;
    if (base < T_TOK*D_DIM){
      const float4 f0 = *(const float4*)(x + base);
      const float4 f1 = *(const float4*)(x + base + 4);
      o.x = f2bf2(f0.x, f0.y); o.y = f2bf2(f0.z, f0.w);
      o.z = f2bf2(f1.x, f1.y); o.w = f2bf2(f1.z, f1.w);
    } else { o.x = o.y = o.z = o.w = 0u; }
    *(uint4*)(xb + base) = o;
  } else if (bx < 24672){
    // w1b / w2b: 18,874,368 elems each, all valid
    const int  wsel = (bx < 15456) ? 0 : 1;
    const long base = ((long)(bx - (wsel ? 15456 : 6240))*256 + tid) << 3;
    const float* src = wsel ? W2 : W1;
    u16* dst = wsel ? w2b : w1b;
    const float4 f0 = *(const float4*)(src + base);
    const float4 f1 = *(const float4*)(src + base + 4);
    uint4 o;
    o.x = f2bf2(f0.x, f0.y); o.y = f2bf2(f0.z, f0.w);
    o.z = f2bf2(f1.x, f1.y); o.w = f2bf2(f1.z, f1.w);
    *(uint4*)(dst + base) = o;
  } else {
    // router: one wave per token
    const int w = (int)(((long)(bx - 24672)*256 + tid) >> 6);
    const int lane = tid & 63;
    if (w >= (int)T_TOK) return;
    const float* xr = x + (long)w * D_DIM;
    float l[8];
#pragma unroll
    for (int e = 0; e < 8; ++e) l[e] = 0.f;
#pragma unroll
    for (int c = 0; c < 3; ++c){
      const float4 xv = *(const float4*)(xr + c*256 + lane*4);
#pragma unroll
      for (int e = 0; e < 8; ++e){
        const float4 wv = *(const float4*)(Wr + (long)e*D_DIM + c*256 + lane*4);
        l[e] += xv.x*wv.x + xv.y*wv.y + xv.z*wv.z + xv.w*wv.w;
      }
    }
#pragma unroll
    for (int e = 0; e < 8; ++e){
#pragma unroll
      for (int off = 32; off > 0; off >>= 1) l[e] += __shfl_xor(l[e], off);
      l[e] += br[e];
    }
    float m = l[0];
#pragma unroll
    for (int e = 1; e < 8; ++e) m = fmaxf(m, l[e]);
    float s = 0.f;
#pragma unroll
    for (int e = 0; e < 8; ++e){ l[e] = __expf(l[e] - m); s += l[e]; }
    const float inv = 1.f / s;
    if (lane == 0){
      float4 p0 = { l[0]*inv, l[1]*inv, l[2]*inv, l[3]*inv };
      float4 p1 = { l[4]*inv, l[5]*inv, l[6]*inv, l[7]*inv };
      *(float4*)(probs + (long)w*8)     = p0;
      *(float4*)(probs + (long)w*8 + 4) = p1;
    }
  }
}

#define FENCE()  __builtin_amdgcn_sched_barrier(0)
#define BAR()    do{ FENCE(); __builtin_amdgcn_s_barrier(); FENCE(); }while(0)
#define LGK0()   do{ asm volatile("s_waitcnt lgkmcnt(0)" ::: "memory"); FENCE(); }while(0)

// read one 16-row MFMA fragment: rows rbase..rbase+15, logical k-chunk c (0..7)
__device__ __forceinline__ s16x8 ld_frag(const u16* S, int rbase, int c, int ln){
  const int r = rbase + ln;
  return *(const s16x8*)(S + (r << 6) + ((c ^ (r & 7)) << 3));
}

// ---------- 256x256 GEMM, BK=64, 4-phase fine interleave (r9, verified) ----------
__device__ __forceinline__ void gemm256(const u16* __restrict__ Ag, long lda,
                                        const u16* __restrict__ Bg, long ldb,
                                        int NT, u16* lds, int tid,
                                        f32x4 (&acc)[8][4]){
  const int l  = tid & 63, w = tid >> 6;
  const int wr = w >> 2,  wc = w & 3;
  const int g4 = l >> 4,  ln = l & 15;

  const int rw = l >> 3;
  const int c8 = (l & 7) ^ rw;
  const u16* gA = Ag + (long)(w*8 + rw) * lda + c8*8;
  const u16* gB = Bg + (long)(w*8 + rw) * ldb + c8*8;
  u16* s0 = lds + w*512;
#define SA(par,T,rnd) gload_lds16(gA + (long)(T)*64 + (long)(rnd)*64*lda, s0 + (par)*32768 + (rnd)*4096)
#define SB(par,T,rnd) gload_lds16(gB + (long)(T)*64 + (long)(rnd)*64*ldb, s0 + (par)*32768 + 16384 + (rnd)*4096)

  // prologue: t0 full (8 loads), t1 early-half (4) -> wait t0 (t1's 4 in flight)
#pragma unroll
  for (int i = 0; i < 4; ++i) SA(0,0,i);
#pragma unroll
  for (int i = 0; i < 4; ++i) SB(0,0,i);
  SA(1,1,0); SB(1,1,0); SA(1,1,2); SB(1,1,1);
  FENCE();
  asm volatile("s_waitcnt vmcnt(4)" ::: "memory");
  BAR();

  for (int kt = 0; kt < NT; ++kt){
    const int par = kt & 1, oth = par ^ 1;
    const u16* As = lds + par * 32768;
    const u16* Bs = As + 16384;
    const bool st1 = (kt + 1 < NT), st2 = (kt + 2 < NT);
    s16x8 aL[4], aH[4], b0[4], b1[4];

    // ---- ph0 ----
#pragma unroll
    for (int ni = 0; ni < 4; ++ni) b0[ni] = ld_frag(Bs, wc*64 + ni*16, g4, ln);
#pragma unroll
    for (int mi = 0; mi < 4; ++mi) aL[mi] = ld_frag(As, wr*128 + mi*16, g4, ln);
    if (st1){ SA(oth, kt+1, 1); SB(oth, kt+1, 2); }
    BAR(); LGK0();
    __builtin_amdgcn_s_setprio(1);
#pragma unroll
    for (int mi = 0; mi < 4; ++mi)
#pragma unroll
      for (int ni = 0; ni < 4; ++ni)
        acc[mi][ni] = __builtin_amdgcn_mfma_f32_16x16x32_bf16(aL[mi], b0[ni], acc[mi][ni], 0, 0, 0);
    __builtin_amdgcn_s_setprio(0);
    BAR();

    // ---- ph1 ----
#pragma unroll
    for (int ni = 0; ni < 4; ++ni) b1[ni] = ld_frag(Bs, wc*64 + ni*16, 4 + g4, ln);
#pragma unroll
    for (int mi = 0; mi < 4; ++mi) aL[mi] = ld_frag(As, wr*128 + mi*16, 4 + g4, ln);
    if (st1){ SA(oth, kt+1, 3); SB(oth, kt+1, 3); }
    BAR(); LGK0();
    __builtin_amdgcn_s_setprio(1);
#pragma unroll
    for (int mi = 0; mi < 4; ++mi)
#pragma unroll
      for (int ni = 0; ni < 4; ++ni)
        acc[mi][ni] = __builtin_amdgcn_mfma_f32_16x16x32_bf16(aL[mi], b1[ni], acc[mi][ni], 0, 0, 0);
    __builtin_amdgcn_s_setprio(0);
    BAR();

    // ---- ph2 ----
#pragma unroll
    for (int mi = 0; mi < 4; ++mi) aH[mi] = ld_frag(As, wr*128 + 64 + mi*16, g4, ln);
    if (st2){ SA(par, kt+2, 0); SB(par, kt+2, 0); }
    BAR(); LGK0();
    __builtin_amdgcn_s_setprio(1);
#pragma unroll
    for (int mi = 0; mi < 4; ++mi)
#pragma unroll
      for (int ni = 0; ni < 4; ++ni)
        acc[mi+4][ni] = __builtin_amdgcn_mfma_f32_16x16x32_bf16(aH[mi], b0[ni], acc[mi+4][ni], 0, 0, 0);
    __builtin_amdgcn_s_setprio(0);
    BAR();

    // ---- ph3 + boundary ----
#pragma unroll
    for (int mi = 0; mi < 4; ++mi) aH[mi] = ld_frag(As, wr*128 + 64 + mi*16, 4 + g4, ln);
    if (st2){ SA(par, kt+2, 2); SB(par, kt+2, 1); }
    BAR(); LGK0();
    __builtin_amdgcn_s_setprio(1);
#pragma unroll
    for (int mi = 0; mi < 4; ++mi)
#pragma unroll
      for (int ni = 0; ni < 4; ++ni)
        acc[mi+4][ni] = __builtin_amdgcn_mfma_f32_16x16x32_bf16(aH[mi], b1[ni], acc[mi+4][ni], 0, 0, 0);
    __builtin_amdgcn_s_setprio(0);

    if (st1){
      FENCE();
      if (st2) asm volatile("s_waitcnt vmcnt(4)" ::: "memory");
      else     asm volatile("s_waitcnt vmcnt(0)" ::: "memory");
      BAR();
    }
  }
#undef SA
#undef SB
}

// ---------- paired dispatch: g2(e2, one token-half) + g1(e1, other half) ----------
// spl==0: g2 full-K (48 tiles), e==0-store / else-RMW (r9 path, verified).
// spl==1: g2 split-K=2 (24 tiles), atomicAdd both splits (bias on sp==0 only) —
//         used only for the final g2(7,B)-alone dispatch (parallelism-starved).
__global__ __launch_bounds__(512, 2) void k_pair(const u16* __restrict__ xb,
                                                 const u16* __restrict__ w1b,
                                                 const float* __restrict__ b1,
                                                 const u16* __restrict__ w2b,
                                                 const float* __restrict__ b2,
                                                 const float* __restrict__ probs,
                                                 float* __restrict__ out,
                                                 const u16* __restrict__ hbR,
                                                 u16* __restrict__ hbW,
                                                 int e2, int t02,
                                                 int e1, int t01, int mt1, int n2,
                                                 int spl){
  __shared__ alignas(16) u16 lds[65536];   // 128 KiB: 2 bufs x (A | B)
  const int tid = threadIdx.x;
  const int l  = tid & 63, w = tid >> 6;
  const int wr = w >> 2,  wc = w & 3;
  const int g4 = l >> 4,  ln = l & 15;
  const int bx = (int)blockIdx.x;
  f32x4 acc[8][4] = {};

  if (bx < n2){
    // ---- g2: XCD-chunked, y-fastest (N-tiles share the A-panel) ----
    const int wg = xcd_chunk(bx, n2);
    int tx, ty, sp, nt, koff;
    if (spl){ ty = wg % 3; sp = (wg / 3) & 1; tx = wg / 6; nt = 24; koff = sp * 1536; }
    else    { ty = wg % 3; sp = 0;            tx = wg / 3; nt = 48; koff = 0; }
    const int m0 = tx << 8, n0 = ty << 8;
    gemm256(hbR + (long)m0 * H_DIM + koff, H_DIM,
            w2b + ((long)e2 * D_DIM + n0) * H_DIM + koff, H_DIM,
            nt, lds, tid, acc);
    float bias[4];
#pragma unroll
    for (int ni = 0; ni < 4; ++ni)
      bias[ni] = (sp == 0) ? b2[(long)e2*D_DIM + n0 + wc*64 + ni*16 + ln] : 0.f;
#pragma unroll
    for (int mi = 0; mi < 8; ++mi){
#pragma unroll
      for (int j = 0; j < 4; ++j){
        const int gt = t02 + m0 + wr*128 + mi*16 + g4*4 + j;
        if (gt < (int)T_TOK){
          const float p = probs[(long)gt*8 + e2];
          float* dst = out + (long)gt * D_DIM + n0 + wc*64;
#pragma unroll
          for (int ni = 0; ni < 4; ++ni){
            const float v = p * (acc[mi][ni][j] + bias[ni]);
            if (spl)          atomicAdd(&dst[ni*16 + ln], v);
            else if (e2 == 0) dst[ni*16 + ln] = v;
            else              dst[ni*16 + ln] += v;
          }
        }
      }
    }
  } else {
    // ---- g1: x-fastest chunk (B-panel reuse along chunk) ----
    const int n1 = (int)gridDim.x - n2;
    const int wg = xcd_chunk(bx - n2, n1);
    const int tx = wg % mt1, ty = wg / mt1;
    const int m0 = tx << 8, n0 = ty << 8;
    gemm256(xb + (long)(t01 + m0) * D_DIM, D_DIM,
            w1b + ((long)e1 * H_DIM + n0) * D_DIM, D_DIM,
            12, lds, tid, acc);
    float bias[4];
#pragma unroll
    for (int ni = 0; ni < 4; ++ni) bias[ni] = b1[(long)e1*H_DIM + n0 + wc*64 + ni*16 + ln];
#pragma unroll
    for (int mi = 0; mi < 8; ++mi){
#pragma unroll
      for (int j = 0; j < 4; ++j){
        const int r = m0 + wr*128 + mi*16 + g4*4 + j;     // half-local row
        u16* dst = hbW + (long)r * H_DIM + n0 + wc*64;
#pragma unroll
        for (int ni = 0; ni < 4; ++ni){
          const float v  = acc[mi][ni][j] + bias[ni];
          const float gl = v / (1.0f + __expf(-1.702f * v));  // quick_gelu
          dst[ni*16 + ln] = f2bf(gl);
        }
      }
    }
  }
}

// ---------- host ----------
extern "C" void kernel_launch(void* const* d_in, const int* in_sizes, int n_in,
                              void* d_out, int out_size, void* d_ws, size_t ws_size,
                              hipStream_t stream){
  const float* x  = (const float*)d_in[0];
  const float* W1 = (const float*)d_in[1];
  const float* b1 = (const float*)d_in[2];
  const float* W2 = (const float*)d_in[3];
  const float* b2 = (const float*)d_in[4];
  const float* Wr = (const float*)d_in[5];
  const float* br = (const float*)d_in[6];
  float* out = (float*)d_out;

  char* ws = (char*)d_ws;
  size_t off = 0;
  auto carve = [&](size_t bytes)->void*{
    void* p = ws + off; off += (bytes + 255) & ~(size_t)255; return p;
  };
  u16*   xb    = (u16*)  carve((size_t)M_PAD * D_DIM * 2);
  u16*   w1b   = (u16*)  carve((size_t)E_NUM * H_DIM * D_DIM * 2);
  u16*   w2b   = (u16*)  carve((size_t)E_NUM * D_DIM * H_DIM * 2);
  float* probs = (float*)carve((size_t)T_TOK * E_NUM * 4);
  u16*   hbA   = (u16*)  carve((size_t)8192 * H_DIM * 2);   // tokens [0, 8192)
  u16*   hbB   = (u16*)  carve((size_t)8448 * H_DIM * 2);   // tokens [8192, 16640)

  // merged prologue: conv x/W1/W2 + router in one dispatch
  k_pro<<<dim3(28784), dim3(256), 0, stream>>>(x, W1, W2, Wr, br, xb, w1b, w2b, probs);

  const int MTA = 32, MTB = 33;      // 256-row tile counts per token-half
  const int T0A = 0,  T0B = 8192;

  auto pair = [&](int e2, const u16* hbR, int t02, int mt2,
                  int e1, u16* hbW, int t01, int mt1, int spl){
    const int n2 = mt2 * (spl ? 6 : 3);
    const int n1 = mt1 * 12;
    k_pair<<<dim3((unsigned)(n2 + n1)), dim3(512), 0, stream>>>(
        xb, w1b, b1, w2b, b2, probs, out, hbR, hbW,
        e2, t02, e1, t01, mt1, n2, spl);
  };

  // ping-pong: D0: g1(0,A); D(2e+1): g2(e,A)+g1(e,B); D(2e+2): g2(e,B)+g1(e+1,A);
  // D16: g2(7,B) alone -> split-K=2 + atomics (starved dispatch)
  pair(0, nullptr, 0, 0, 0, hbA, T0A, MTA, 0);
  for (int e = 0; e < 8; ++e){
    pair(e, hbA, T0A, MTA, e, hbB, T0B, MTB, 0);
    if (e < 7) pair(e, hbB, T0B, MTB, e + 1, hbA, T0A, MTA, 0);
  }
  pair(7, hbB, T0B, MTB, 0, nullptr, 0, 0, 1);
}